// Round 1
// baseline (532.460 us; speedup 1.0000x reference)
//
#include <hip/hip_runtime.h>
#include <math.h>

#define VOCAB 50257
#define PAD_IDX 0

// Kernel 1: one block per row. Computes the full row sum S_r with vectorized
// loads, then thread 0 applies the closed-form per-row loss:
//   res = K - conf*x[t] - sv*(S - x[0] - x[t])    (0 if t == PAD_IDX)
__global__ __launch_bounds__(256) void row_loss_kernel(
    const float* __restrict__ x,      // [N, V] log-probs
    const int* __restrict__ tgt,      // [N]
    float* __restrict__ partial,      // [N] per-row loss
    int V, float K, float conf, float sv) {
    const int row = blockIdx.x;
    const int tid = threadIdx.x;
    const float* __restrict__ xr = x + (size_t)row * (size_t)V;

    // Row base is only 4B-aligned (V odd). Scalar head until 16B alignment.
    const int head = (int)((4u - (((size_t)xr >> 2) & 3u)) & 3u);
    float local = 0.0f;
    if (tid < head) local += xr[tid];

    const float* xa = xr + head;
    const int nrem = V - head;
    const int n4 = nrem >> 2;
    const float4* __restrict__ x4 = (const float4*)xa;
    for (int i = tid; i < n4; i += 256) {
        float4 v = x4[i];
        local += (v.x + v.y) + (v.z + v.w);
    }
    // tail
    for (int i = (n4 << 2) + tid; i < nrem; i += 256) local += xa[i];

    // wave (64-lane) shuffle reduce, then cross-wave via LDS
    #pragma unroll
    for (int off = 32; off > 0; off >>= 1) local += __shfl_down(local, off, 64);
    __shared__ float wsum[4];
    const int lane = tid & 63;
    const int wid = tid >> 6;
    if (lane == 0) wsum[wid] = local;
    __syncthreads();
    if (tid == 0) {
        const float S = (wsum[0] + wsum[1]) + (wsum[2] + wsum[3]);
        const int t = tgt[row];
        float res = 0.0f;
        if (t != PAD_IDX) {
            const float xt = xr[t];
            const float x0 = xr[0];
            res = K - conf * xt - sv * (S - x0 - xt);
        }
        partial[row] = res;
    }
}

// Kernel 2: single block reduces N per-row partials to the scalar output.
__global__ __launch_bounds__(256) void final_reduce_kernel(
    const float* __restrict__ partial, float* __restrict__ out, int n) {
    const int tid = threadIdx.x;
    float local = 0.0f;
    for (int i = tid; i < n; i += 256) local += partial[i];
    #pragma unroll
    for (int off = 32; off > 0; off >>= 1) local += __shfl_down(local, off, 64);
    __shared__ float wsum[4];
    const int lane = tid & 63;
    const int wid = tid >> 6;
    if (lane == 0) wsum[wid] = local;
    __syncthreads();
    if (tid == 0) out[0] = (wsum[0] + wsum[1]) + (wsum[2] + wsum[3]);
}

extern "C" void kernel_launch(void* const* d_in, const int* in_sizes, int n_in,
                              void* d_out, int out_size, void* d_ws, size_t ws_size,
                              hipStream_t stream) {
    const float* x = (const float*)d_in[0];     // [N, V] fp32
    const int* tgt = (const int*)d_in[1];       // [N] int32
    float* out = (float*)d_out;
    float* partial = (float*)d_ws;              // N floats of scratch

    const int V = VOCAB;
    const int N = in_sizes[1];                  // 8*256 = 2048 rows

    const double confidence = 0.9;
    const double sv = 0.1 / (double)(V - 2);
    // K = conf*log(conf) + (V-2)*sv*log(sv) = conf*log(conf) + 0.1*log(sv)
    const double K = confidence * log(confidence) + 0.1 * log(sv);

    row_loss_kernel<<<N, 256, 0, stream>>>(x, tgt, partial, V,
                                           (float)K, (float)confidence, (float)sv);
    final_reduce_kernel<<<1, 256, 0, stream>>>(partial, out, N);
}